// Round 14
// baseline (153.643 us; speedup 1.0000x reference)
//
#include <hip/hip_runtime.h>
#include <math.h>

#define S4_H   128
#define S4_HP  136          // padded leading dim (dword stride 136 ≡ 8 mod 32)
#define S4_T   12
#define S4_TT  48           // 4 seqs * 12 timesteps
#define S4_S2  32
#define S4_SEQ 4
#define S4_NL  2
#define S4_N   1024
#define S4_BN  (16 * 1024)
#define S4_GRID (S4_BN / S4_SEQ)   // 4096 blocks; 4096 % 8 == 0 -> bijective swizzle

typedef float f4 __attribute__((ext_vector_type(4)));
typedef short s8v __attribute__((ext_vector_type(8)));   // 8 bf16 bit-patterns

__device__ __forceinline__ unsigned short f2bf(float f) {
  unsigned int u = __builtin_bit_cast(unsigned int, f);
  u += 0x7fffu + ((u >> 16) & 1u);   // RNE
  return (unsigned short)(u >> 16);
}

// gelu(x) ~= x * sigmoid(1.5957691x(1 + 0.044715x^2))  (tanh form)
__device__ __forceinline__ float fast_gelu(float x) {
  const float u = 1.5957691216057308f * x * fmaf(0.044715f, x * x, 1.0f);
  return x * __builtin_amdgcn_rcpf(1.0f + __expf(-u));
}
__device__ __forceinline__ float fast_sigmoid(float g) {
  return __builtin_amdgcn_rcpf(1.0f + __expf(-g));
}

// ---------------------------------------------------------------------------
// S4D kernel row: k[h][t] = 2*Re( sum_n C_n * exp(dtA_n)^t ), ZOH discretized.
// ---------------------------------------------------------------------------
__device__ __forceinline__ void s4d_row(const float* __restrict__ log_A_real,
                                        const float* __restrict__ A_imag,
                                        const float* __restrict__ C_re,
                                        const float* __restrict__ C_im,
                                        const float* __restrict__ log_dt,
                                        int lh, float* kk) {
  const float dt = expf(log_dt[lh]);
#pragma unroll
  for (int t = 0; t < S4_T; ++t) kk[t] = 0.f;
  const int base = lh * S4_S2;
  for (int n = 0; n < S4_S2; ++n) {
    const float ar = -expf(log_A_real[base + n]);
    const float ai = A_imag[base + n];
    const float m  = expf(ar * dt);
    const float di = ai * dt;
    float sdi, cdi;
    sincosf(di, &sdi, &cdi);
    const float er = m * cdi, ei = m * sdi;           // exp(dt*A)
    const float inv = 1.0f / (ar * ar + ai * ai);
    const float x0 = er - 1.0f;
    const float qr = (x0 * ar + ei * ai) * inv;       // (exp(dtA)-1)/A
    const float qi = (ei * ar - x0 * ai) * inv;
    const float c0r = C_re[base + n], c0i = C_im[base + n];
    const float cr = c0r * qr - c0i * qi;             // C_tilde
    const float ci = c0r * qi + c0i * qr;
    float vr = 1.f, vi = 0.f;                         // V = exp(dtA)^t
#pragma unroll
    for (int t = 0; t < S4_T; ++t) {
      kk[t] = fmaf(cr, vr, fmaf(-ci, vi, kk[t]));
      const float nvr = vr * er - vi * ei;
      vi = vr * ei + vi * er;
      vr = nvr;
    }
  }
#pragma unroll
  for (int t = 0; t < S4_T; ++t) kk[t] *= 2.0f;
}

// prep: W fp32 -> bf16 bits in ws, and S4D kernel k into ws.
__global__ __launch_bounds__(256) void s4_prep(
    const float* __restrict__ oW, const float* __restrict__ lAr,
    const float* __restrict__ Aim, const float* __restrict__ Cre,
    const float* __restrict__ Cim, const float* __restrict__ ldt,
    unsigned short* __restrict__ Wbf, float* __restrict__ kout) {
  const int tid = blockIdx.x * 256 + (int)threadIdx.x;
  const int i = tid * 4;
  if (i < S4_NL * 2 * S4_H * S4_H) {
    const f4 v = *reinterpret_cast<const f4*>(&oW[i]);
    ushort4 o;
    o.x = f2bf(v[0]); o.y = f2bf(v[1]); o.z = f2bf(v[2]); o.w = f2bf(v[3]);
    *reinterpret_cast<ushort4*>(&Wbf[i]) = o;
  }
  if (tid < S4_NL * S4_H) {
    float kk[S4_T];
    s4d_row(lAr, Aim, Cre, Cim, ldt, tid, kk);
#pragma unroll
    for (int t = 0; t < S4_T; ++t) kout[tid * S4_T + t] = kk[t];
  }
}

// ---------------------------------------------------------------------------
// Fused S4 block, 512 threads (8 waves), R3 memory patterns for hb/gb.
// W-fragment global loads hoisted above the conv phase (L2 latency hidden
// under conv compute). Output phase: conflict-free row reads + 48-B/thread
// stores (clean at VGPR>=40 -- the R6-R12 write amplification was spills).
// ---------------------------------------------------------------------------
__global__ __launch_bounds__(512, 4) void s4_512(
    const float* __restrict__ x, const float* __restrict__ enc_W,
    const float* __restrict__ enc_b, const float* __restrict__ Dp,
    const float* __restrict__ out_b, const float* __restrict__ ln_g,
    const float* __restrict__ ln_b, const float* __restrict__ sc_W,
    const float* __restrict__ sc_b, const unsigned short* __restrict__ Wbf,
    const float* __restrict__ kws, float* __restrict__ out) {
  __shared__ __align__(16) float hb[S4_TT][S4_HP];           // 26112 B (fp32)
  __shared__ __align__(16) unsigned short gb[S4_TT][S4_HP];  // 13056 B (bf16)
  __shared__ __align__(16) float xb[S4_SEQ][S4_T];           // 192 B

  const int tid  = threadIdx.x;
  const int w    = tid >> 6;          // wave 0..7
  const int lane = tid & 63;
  const int s    = tid >> 7;          // owned sequence (conv/output), 0..3
  const int h    = tid & (S4_H - 1);  // owned channel (conv/output)
  const int r    = lane & 15;         // GEMM: N index / A row offset
  const int q    = lane >> 4;         // GEMM: k-group / D row group
  // bijective XCD swizzle: XCD x handles contiguous seq range
  const int bid  = blockIdx.x;
  const int swz  = (bid & 7) * (S4_GRID / 8) + (bid >> 3);
  const int seq0 = swz * S4_SEQ;

  if (tid < S4_SEQ * S4_T) {
    const int ss = tid / S4_T, t = tid - ss * S4_T;
    xb[ss][t] = x[(seq0 + ss) * S4_T + t];
  }
  __syncthreads();

  for (int l = 0; l < S4_NL; ++l) {
    // ---- W-fragment prefetch (depends only on l): issue before conv so
    //      L2 latency hides under conv compute ----
    s8v afV[4], afG[4];
    {
      const unsigned short* WL = Wbf + (size_t)l * 2 * S4_H * S4_H;
      const unsigned short* wVp = WL + (size_t)(w * 16 + r) * S4_H + q * 8;
      const unsigned short* wGp =
          WL + (size_t)((8 + w) * 16 + r) * S4_H + q * 8;
#pragma unroll
      for (int ks = 0; ks < 4; ++ks) {
        afV[ks] = *(const s8v*)(wVp + ks * 32);
        afG[ks] = *(const s8v*)(wGp + ks * 32);
      }
    }
    // ---- conv phase (1 row per thread); l==0 fuses encoder & seeds hb ----
    {
      const float* kp = &kws[(l * S4_H + h) * S4_T];
      const f4 k0 = *(const f4*)(kp), k1 = *(const f4*)(kp + 4),
               k2 = *(const f4*)(kp + 8);
      const float kr[S4_T] = {k0[0], k0[1], k0[2], k0[3], k1[0], k1[1],
                              k1[2], k1[3], k2[0], k2[1], k2[2], k2[3]};
      const float dl = Dp[l * S4_H + h];
      float z[S4_T];
      if (l == 0) {
        const float ew = enc_W[h], eb = enc_b[h];
#pragma unroll
        for (int t = 0; t < S4_T; ++t) {
          z[t] = fmaf(xb[s][t], ew, eb);
          hb[s * S4_T + t][h] = z[t];
        }
      } else {
#pragma unroll
        for (int t = 0; t < S4_T; ++t) z[t] = hb[s * S4_T + t][h];
      }
#pragma unroll
      for (int t = 0; t < S4_T; ++t) {
        float a = dl * z[t];
#pragma unroll
        for (int ss = 0; ss <= t; ++ss) a = fmaf(kr[t - ss], z[ss], a);
        gb[s * S4_T + t][h] = f2bf(fast_gelu(a));
      }
    }
    __syncthreads();
    // ---- channel mix: wave w owns val tile w, gate tile 8+w ----
    {
      f4 accV[3] = {}, accG[3] = {};
#pragma unroll
      for (int ks = 0; ks < 4; ++ks) {
#pragma unroll
        for (int n = 0; n < 3; ++n) {
          const s8v bfv =
              *(const s8v*)(&gb[n * 16 + r][ks * 32 + q * 8]);
          accV[n] = __builtin_amdgcn_mfma_f32_16x16x32_bf16(afV[ks], bfv,
                                                            accV[n], 0, 0, 0);
          accG[n] = __builtin_amdgcn_mfma_f32_16x16x32_bf16(afG[ks], bfv,
                                                            accG[n], 0, 0, 0);
        }
      }
      // GLU + bias + residual RMW into hb (unique 16B quads per lane)
      const int oV = w * 16 + 4 * q;
      const f4 bV = *(const f4*)&out_b[l * 2 * S4_H + oV];
      const f4 bG = *(const f4*)&out_b[l * 2 * S4_H + S4_H + oV];
#pragma unroll
      for (int n = 0; n < 3; ++n) {
        f4* hp = reinterpret_cast<f4*>(&hb[n * 16 + r][oV]);
        f4 hv = *hp;
#pragma unroll
        for (int j = 0; j < 4; ++j) {
          const float a = accV[n][j] + bV[j];
          const float g = accG[n][j] + bG[j];
          hv[j] += a * fast_sigmoid(g);
        }
        *hp = hv;
      }
    }
    __syncthreads();
    // ---- LayerNorm in-place: 8 lanes per tt column ----
    {
      const int col = tid >> 3;       // 0..63 (cols >=48 idle)
      const int q8  = tid & 7;
      if (col < S4_TT) {
        float s1 = 0.f, s2 = 0.f;
#pragma unroll
        for (int j = 0; j < 4; ++j) {
          const f4 v = *(const f4*)&hb[col][(q8 + 8 * j) * 4];
          s1 += v[0] + v[1] + v[2] + v[3];
          s2 = fmaf(v[0], v[0], s2); s2 = fmaf(v[1], v[1], s2);
          s2 = fmaf(v[2], v[2], s2); s2 = fmaf(v[3], v[3], s2);
        }
        s1 += __shfl_xor(s1, 1, 8); s1 += __shfl_xor(s1, 2, 8);
        s1 += __shfl_xor(s1, 4, 8);
        s2 += __shfl_xor(s2, 1, 8); s2 += __shfl_xor(s2, 2, 8);
        s2 += __shfl_xor(s2, 4, 8);
        const float mu   = s1 * (1.0f / S4_H);
        const float var  = s2 * (1.0f / S4_H) - mu * mu;
        const float rstd = rsqrtf(var + 1e-5f);
#pragma unroll
        for (int j = 0; j < 4; ++j) {
          const int e = (q8 + 8 * j) * 4;
          f4 v = *(const f4*)&hb[col][e];
          const f4 gg = *(const f4*)&ln_g[l * S4_H + e];
          const f4 bb = *(const f4*)&ln_b[l * S4_H + e];
#pragma unroll
          for (int jj = 0; jj < 4; ++jj)
            v[jj] = fmaf((v[jj] - mu) * rstd, gg[jj], bb[jj]);
          *(f4*)&hb[col][e] = v;
        }
      }
    }
    __syncthreads();
  }
  // ---- output (B,H,N,T) + 1x1 conv shortcut (1 row per thread) ----
  // hb reads are row-fixed (contiguous dwords per instruction): conflict-free.
  // 48-B/thread scattered stores are HBM-clean when there are no spills.
  {
    const float sw = sc_W[h], sb = sc_b[h];
    const int bn = seq0 + s;
    const int b = bn >> 10, n = bn & (S4_N - 1);
    float* op = out + (size_t)((b * S4_H + h) * S4_N + n) * S4_T;
#pragma unroll
    for (int qq = 0; qq < 3; ++qq) {
      f4 o;
#pragma unroll
      for (int t4 = 0; t4 < 4; ++t4) {
        const int t = qq * 4 + t4;
        o[t4] = hb[s * S4_T + t][h] + fmaf(sw, xb[s][t], sb);
      }
      *reinterpret_cast<f4*>(op + qq * 4) = o;
    }
  }
}

// ---------------------------------------------------------------------------
// Fallback (no workspace): round-1 fp32 kernel, inline-k variant (exact math).
// ---------------------------------------------------------------------------
#define S4F_SEQ 4
__global__ __launch_bounds__(256) void s4_main_f32(
    const float* __restrict__ x, const float* __restrict__ enc_W,
    const float* __restrict__ enc_b, const float* __restrict__ log_A_real,
    const float* __restrict__ A_imag, const float* __restrict__ C_re,
    const float* __restrict__ C_im, const float* __restrict__ log_dt,
    const float* __restrict__ Dp, const float* __restrict__ out_W,
    const float* __restrict__ out_b, const float* __restrict__ ln_g,
    const float* __restrict__ ln_b, const float* __restrict__ sc_W,
    const float* __restrict__ sc_b, float* __restrict__ out) {
  __shared__ __align__(16) float hbuf[S4F_SEQ][S4_H][S4_T];
  __shared__ __align__(16) float gbuf[S4F_SEQ][S4_H][S4_T];
  __shared__ __align__(16) float kbuf[S4_NL][S4_H][S4_T];
  __shared__ __align__(16) float xbuf[S4F_SEQ][S4_T];
  const int tid = threadIdx.x;
  const int seq0 = blockIdx.x * S4F_SEQ;
  if (tid < S4F_SEQ * S4_T) {
    const int s = tid / S4_T, t = tid - s * S4_T;
    xbuf[s][t] = x[(seq0 + s) * S4_T + t];
  }
  {
    float kk[S4_T];
    s4d_row(log_A_real, A_imag, C_re, C_im, log_dt, tid, kk);
#pragma unroll
    for (int t = 0; t < S4_T; ++t) (&kbuf[0][0][0])[tid * S4_T + t] = kk[t];
  }
  __syncthreads();
  for (int r = tid; r < S4F_SEQ * S4_H; r += 256) {
    const int s = r >> 7, h = r & (S4_H - 1);
    const float ew = enc_W[h], eb = enc_b[h];
#pragma unroll
    for (int t = 0; t < S4_T; ++t) hbuf[s][h][t] = fmaf(xbuf[s][t], ew, eb);
  }
  for (int l = 0; l < S4_NL; ++l) {
    __syncthreads();
    for (int r = tid; r < S4F_SEQ * S4_H; r += 256) {
      const int s = r >> 7, h = r & (S4_H - 1);
      float z[S4_T], kr[S4_T];
#pragma unroll
      for (int t = 0; t < S4_T; ++t) {
        z[t] = hbuf[s][h][t];
        kr[t] = kbuf[l][h][t];
      }
      const float dl = Dp[l * S4_H + h];
#pragma unroll
      for (int t = 0; t < S4_T; ++t) {
        float a = dl * z[t];
#pragma unroll
        for (int ss = 0; ss <= t; ++ss) a = fmaf(kr[t - ss], z[ss], a);
        gbuf[s][h][t] = 0.5f * a * (1.0f + erff(a * 0.70710678118654752f));
      }
    }
    __syncthreads();
    {
      const int op = tid & (S4_H - 1);
      const int sg = tid >> 7;
      const float* __restrict__ W0 = out_W + (size_t)(l * 2 * S4_H + op) * S4_H;
      const float* __restrict__ W1 = W0 + S4_H * S4_H;
      float acc0[2][S4_T], acc1[2][S4_T];
#pragma unroll
      for (int s2 = 0; s2 < 2; ++s2)
#pragma unroll
        for (int t = 0; t < S4_T; ++t) { acc0[s2][t] = 0.f; acc1[s2][t] = 0.f; }
      for (int h0 = 0; h0 < S4_H; h0 += 4) {
        const float4 w0 = *reinterpret_cast<const float4*>(W0 + h0);
        const float4 w1 = *reinterpret_cast<const float4*>(W1 + h0);
        const float w0a[4] = {w0.x, w0.y, w0.z, w0.w};
        const float w1a[4] = {w1.x, w1.y, w1.z, w1.w};
#pragma unroll
        for (int j = 0; j < 4; ++j) {
#pragma unroll
          for (int s2 = 0; s2 < 2; ++s2) {
            const float* gp = &gbuf[2 * sg + s2][h0 + j][0];
            const float4 ga = *reinterpret_cast<const float4*>(gp);
            const float4 gc = *reinterpret_cast<const float4*>(gp + 4);
            const float4 ge = *reinterpret_cast<const float4*>(gp + 8);
            const float gg[S4_T] = {ga.x, ga.y, ga.z, ga.w, gc.x, gc.y,
                                    gc.z, gc.w, ge.x, ge.y, ge.z, ge.w};
#pragma unroll
            for (int t = 0; t < S4_T; ++t) {
              acc0[s2][t] = fmaf(w0a[j], gg[t], acc0[s2][t]);
              acc1[s2][t] = fmaf(w1a[j], gg[t], acc1[s2][t]);
            }
          }
        }
      }
      const float b0 = out_b[l * 2 * S4_H + op];
      const float b1 = out_b[l * 2 * S4_H + S4_H + op];
#pragma unroll
      for (int s2 = 0; s2 < 2; ++s2) {
        const int seq = 2 * sg + s2;
#pragma unroll
        for (int t = 0; t < S4_T; ++t) {
          const float a = acc0[s2][t] + b0;
          const float g = acc1[s2][t] + b1;
          hbuf[seq][op][t] += a * (1.0f / (1.0f + expf(-g)));
        }
      }
    }
    __syncthreads();
    {
      const int col = tid >> 2;
      const int ing = tid & 3;
      if (col < S4F_SEQ * S4_T) {
        const int s = col / S4_T, t = col - s * S4_T;
        float s1 = 0.f, s2v = 0.f;
#pragma unroll
        for (int i = 0; i < S4_H / 4; ++i) {
          const float v = hbuf[s][ing * 32 + i][t];
          s1 += v;
          s2v = fmaf(v, v, s2v);
        }
        s1 += __shfl_xor(s1, 1, 4); s1 += __shfl_xor(s1, 2, 4);
        s2v += __shfl_xor(s2v, 1, 4); s2v += __shfl_xor(s2v, 2, 4);
        const float mu = s1 * (1.0f / S4_H);
        const float var = s2v * (1.0f / S4_H) - mu * mu;
        const float rstd = rsqrtf(var + 1e-5f);
#pragma unroll
        for (int i = 0; i < S4_H / 4; ++i) {
          const int h = ing * 32 + i;
          const float v = hbuf[s][h][t];
          hbuf[s][h][t] =
              fmaf((v - mu) * rstd, ln_g[l * S4_H + h], ln_b[l * S4_H + h]);
        }
      }
    }
  }
  __syncthreads();
  for (int r = tid; r < S4F_SEQ * S4_H; r += 256) {
    const int s = r >> 7, h = r & (S4_H - 1);
    const int bn = seq0 + s;
    const int b = bn >> 10, n = bn & (S4_N - 1);
    const float sw = sc_W[h], sb = sc_b[h];
#pragma unroll
    for (int q = 0; q < 3; ++q) {
      float4 o;
      const float4 hv0 = *reinterpret_cast<const float4*>(&hbuf[s][h][4 * q]);
      const float4 xv = *reinterpret_cast<const float4*>(&xbuf[s][4 * q]);
      o.x = hv0.x + fmaf(sw, xv.x, sb);
      o.y = hv0.y + fmaf(sw, xv.y, sb);
      o.z = hv0.z + fmaf(sw, xv.z, sb);
      o.w = hv0.w + fmaf(sw, xv.w, sb);
      reinterpret_cast<float4*>(out + (size_t)((b * S4_H + h) * S4_N + n) *
                                          S4_T)[q] = o;
    }
  }
}

extern "C" void kernel_launch(void* const* d_in, const int* in_sizes, int n_in,
                              void* d_out, int out_size, void* d_ws,
                              size_t ws_size, hipStream_t stream) {
  const float* x     = (const float*)d_in[0];
  const float* enc_W = (const float*)d_in[1];
  const float* enc_b = (const float*)d_in[2];
  const float* lAr   = (const float*)d_in[3];
  const float* Aim   = (const float*)d_in[4];
  const float* Cre   = (const float*)d_in[5];
  const float* Cim   = (const float*)d_in[6];
  const float* ldt   = (const float*)d_in[7];
  const float* Dp    = (const float*)d_in[8];
  const float* oW    = (const float*)d_in[9];
  const float* ob    = (const float*)d_in[10];
  const float* lg    = (const float*)d_in[11];
  const float* lb    = (const float*)d_in[12];
  const float* scW   = (const float*)d_in[13];
  const float* scb   = (const float*)d_in[14];
  float* out = (float*)d_out;

  const size_t wbytes = (size_t)(S4_NL * 2 * S4_H * S4_H) * sizeof(unsigned short); // 131072
  const size_t kbytes = (size_t)(S4_NL * S4_H * S4_T) * sizeof(float);              // 12288
  if (ws_size >= wbytes + kbytes) {
    unsigned short* Wbf = (unsigned short*)d_ws;
    float* kws = (float*)((char*)d_ws + wbytes);
    s4_prep<<<64, 256, 0, stream>>>(oW, lAr, Aim, Cre, Cim, ldt, Wbf, kws);
    s4_512<<<S4_GRID, 512, 0, stream>>>(x, enc_W, enc_b, Dp, ob, lg,
                                        lb, scW, scb, Wbf, kws, out);
  } else {
    s4_main_f32<<<S4_BN / S4F_SEQ, 256, 0, stream>>>(
        x, enc_W, enc_b, lAr, Aim, Cre, Cim, ldt, Dp, oW, ob, lg, lb, scW,
        scb, out);
  }
}

// Round 15
// 138.229 us; speedup vs baseline: 1.1115x; 1.1115x over previous
//
#include <hip/hip_runtime.h>
#include <math.h>

#define S4_H   128
#define S4_HP  136          // padded leading dim (dword stride 136 ≡ 8 mod 32)
#define S4_T   12
#define S4_TT  48           // 4 seqs * 12 timesteps
#define S4_S2  32
#define S4_SEQ 4
#define S4_NL  2
#define S4_N   1024
#define S4_BN  (16 * 1024)
#define S4_GRID (S4_BN / S4_SEQ)   // 4096 blocks; 4096 % 8 == 0 -> bijective swizzle

typedef float f4 __attribute__((ext_vector_type(4)));
typedef short s8v __attribute__((ext_vector_type(8)));   // 8 bf16 bit-patterns

__device__ __forceinline__ unsigned short f2bf(float f) {
  unsigned int u = __builtin_bit_cast(unsigned int, f);
  u += 0x7fffu + ((u >> 16) & 1u);   // RNE
  return (unsigned short)(u >> 16);
}

// gelu(x) ~= x * sigmoid(1.5957691x(1 + 0.044715x^2))  (tanh form)
__device__ __forceinline__ float fast_gelu(float x) {
  const float u = 1.5957691216057308f * x * fmaf(0.044715f, x * x, 1.0f);
  return x * __builtin_amdgcn_rcpf(1.0f + __expf(-u));
}
__device__ __forceinline__ float fast_sigmoid(float g) {
  return __builtin_amdgcn_rcpf(1.0f + __expf(-g));
}

// ---------------------------------------------------------------------------
// S4D kernel row: k[h][t] = 2*Re( sum_n C_n * exp(dtA_n)^t ), ZOH discretized.
// ---------------------------------------------------------------------------
__device__ __forceinline__ void s4d_row(const float* __restrict__ log_A_real,
                                        const float* __restrict__ A_imag,
                                        const float* __restrict__ C_re,
                                        const float* __restrict__ C_im,
                                        const float* __restrict__ log_dt,
                                        int lh, float* kk) {
  const float dt = expf(log_dt[lh]);
#pragma unroll
  for (int t = 0; t < S4_T; ++t) kk[t] = 0.f;
  const int base = lh * S4_S2;
  for (int n = 0; n < S4_S2; ++n) {
    const float ar = -expf(log_A_real[base + n]);
    const float ai = A_imag[base + n];
    const float m  = expf(ar * dt);
    const float di = ai * dt;
    float sdi, cdi;
    sincosf(di, &sdi, &cdi);
    const float er = m * cdi, ei = m * sdi;           // exp(dt*A)
    const float inv = 1.0f / (ar * ar + ai * ai);
    const float x0 = er - 1.0f;
    const float qr = (x0 * ar + ei * ai) * inv;       // (exp(dtA)-1)/A
    const float qi = (ei * ar - x0 * ai) * inv;
    const float c0r = C_re[base + n], c0i = C_im[base + n];
    const float cr = c0r * qr - c0i * qi;             // C_tilde
    const float ci = c0r * qi + c0i * qr;
    float vr = 1.f, vi = 0.f;                         // V = exp(dtA)^t
#pragma unroll
    for (int t = 0; t < S4_T; ++t) {
      kk[t] = fmaf(cr, vr, fmaf(-ci, vi, kk[t]));
      const float nvr = vr * er - vi * ei;
      vi = vr * ei + vi * er;
      vr = nvr;
    }
  }
#pragma unroll
  for (int t = 0; t < S4_T; ++t) kk[t] *= 2.0f;
}

// prep: W fp32 -> bf16 bits in ws, and S4D kernel k into ws.
__global__ __launch_bounds__(256) void s4_prep(
    const float* __restrict__ oW, const float* __restrict__ lAr,
    const float* __restrict__ Aim, const float* __restrict__ Cre,
    const float* __restrict__ Cim, const float* __restrict__ ldt,
    unsigned short* __restrict__ Wbf, float* __restrict__ kout) {
  const int tid = blockIdx.x * 256 + (int)threadIdx.x;
  const int i = tid * 4;
  if (i < S4_NL * 2 * S4_H * S4_H) {
    const f4 v = *reinterpret_cast<const f4*>(&oW[i]);
    ushort4 o;
    o.x = f2bf(v[0]); o.y = f2bf(v[1]); o.z = f2bf(v[2]); o.w = f2bf(v[3]);
    *reinterpret_cast<ushort4*>(&Wbf[i]) = o;
  }
  if (tid < S4_NL * S4_H) {
    float kk[S4_T];
    s4d_row(lAr, Aim, Cre, Cim, ldt, tid, kk);
#pragma unroll
    for (int t = 0; t < S4_T; ++t) kout[tid * S4_T + t] = kk[t];
  }
}

// ---------------------------------------------------------------------------
// Fused S4 block, 512 threads (8 waves), R3 memory patterns for hb/gb.
// W-fragment loads issued inside the GEMM phase (TLP hides their latency;
// hoisting them regressed scheduling -- R14). Output: conflict-free row
// reads + 48-B/thread stores (clean since VGPR>=40, no spills).
// ---------------------------------------------------------------------------
__global__ __launch_bounds__(512, 4) void s4_512(
    const float* __restrict__ x, const float* __restrict__ enc_W,
    const float* __restrict__ enc_b, const float* __restrict__ Dp,
    const float* __restrict__ out_b, const float* __restrict__ ln_g,
    const float* __restrict__ ln_b, const float* __restrict__ sc_W,
    const float* __restrict__ sc_b, const unsigned short* __restrict__ Wbf,
    const float* __restrict__ kws, float* __restrict__ out) {
  __shared__ __align__(16) float hb[S4_TT][S4_HP];           // 26112 B (fp32)
  __shared__ __align__(16) unsigned short gb[S4_TT][S4_HP];  // 13056 B (bf16)
  __shared__ __align__(16) float xb[S4_SEQ][S4_T];           // 192 B

  const int tid  = threadIdx.x;
  const int w    = tid >> 6;          // wave 0..7
  const int lane = tid & 63;
  const int s    = tid >> 7;          // owned sequence (conv/output), 0..3
  const int h    = tid & (S4_H - 1);  // owned channel (conv/output)
  const int r    = lane & 15;         // GEMM: N index / A row offset
  const int q    = lane >> 4;         // GEMM: k-group / D row group
  // bijective XCD swizzle: XCD x handles contiguous seq range
  const int bid  = blockIdx.x;
  const int swz  = (bid & 7) * (S4_GRID / 8) + (bid >> 3);
  const int seq0 = swz * S4_SEQ;

  if (tid < S4_SEQ * S4_T) {
    const int ss = tid / S4_T, t = tid - ss * S4_T;
    xb[ss][t] = x[(seq0 + ss) * S4_T + t];
  }
  __syncthreads();

  for (int l = 0; l < S4_NL; ++l) {
    // ---- conv phase (1 row per thread); l==0 fuses encoder & seeds hb ----
    {
      const float* kp = &kws[(l * S4_H + h) * S4_T];
      const f4 k0 = *(const f4*)(kp), k1 = *(const f4*)(kp + 4),
               k2 = *(const f4*)(kp + 8);
      const float kr[S4_T] = {k0[0], k0[1], k0[2], k0[3], k1[0], k1[1],
                              k1[2], k1[3], k2[0], k2[1], k2[2], k2[3]};
      const float dl = Dp[l * S4_H + h];
      float z[S4_T];
      if (l == 0) {
        const float ew = enc_W[h], eb = enc_b[h];
#pragma unroll
        for (int t = 0; t < S4_T; ++t) {
          z[t] = fmaf(xb[s][t], ew, eb);
          hb[s * S4_T + t][h] = z[t];
        }
      } else {
#pragma unroll
        for (int t = 0; t < S4_T; ++t) z[t] = hb[s * S4_T + t][h];
      }
#pragma unroll
      for (int t = 0; t < S4_T; ++t) {
        float a = dl * z[t];
#pragma unroll
        for (int ss = 0; ss <= t; ++ss) a = fmaf(kr[t - ss], z[ss], a);
        gb[s * S4_T + t][h] = f2bf(fast_gelu(a));
      }
    }
    __syncthreads();
    // ---- channel mix: wave w owns val tile w, gate tile 8+w ----
    {
      f4 accV[3] = {}, accG[3] = {};
      const unsigned short* WL = Wbf + (size_t)l * 2 * S4_H * S4_H;
      const unsigned short* wVp = WL + (size_t)(w * 16 + r) * S4_H + q * 8;
      const unsigned short* wGp = WL + (size_t)((8 + w) * 16 + r) * S4_H + q * 8;
#pragma unroll
      for (int ks = 0; ks < 4; ++ks) {
        const s8v afV = *(const s8v*)(wVp + ks * 32);
        const s8v afG = *(const s8v*)(wGp + ks * 32);
#pragma unroll
        for (int n = 0; n < 3; ++n) {
          const s8v bfv =
              *(const s8v*)(&gb[n * 16 + r][ks * 32 + q * 8]);
          accV[n] = __builtin_amdgcn_mfma_f32_16x16x32_bf16(afV, bfv, accV[n],
                                                            0, 0, 0);
          accG[n] = __builtin_amdgcn_mfma_f32_16x16x32_bf16(afG, bfv, accG[n],
                                                            0, 0, 0);
        }
      }
      // GLU + bias + residual RMW into hb (unique 16B quads per lane)
      const int oV = w * 16 + 4 * q;
      const f4 bV = *(const f4*)&out_b[l * 2 * S4_H + oV];
      const f4 bG = *(const f4*)&out_b[l * 2 * S4_H + S4_H + oV];
#pragma unroll
      for (int n = 0; n < 3; ++n) {
        f4* hp = reinterpret_cast<f4*>(&hb[n * 16 + r][oV]);
        f4 hv = *hp;
#pragma unroll
        for (int j = 0; j < 4; ++j) {
          const float a = accV[n][j] + bV[j];
          const float g = accG[n][j] + bG[j];
          hv[j] += a * fast_sigmoid(g);
        }
        *hp = hv;
      }
    }
    __syncthreads();
    // ---- LayerNorm in-place: 8 lanes per tt column ----
    {
      const int col = tid >> 3;       // 0..63 (cols >=48 idle)
      const int q8  = tid & 7;
      if (col < S4_TT) {
        float s1 = 0.f, s2 = 0.f;
#pragma unroll
        for (int j = 0; j < 4; ++j) {
          const f4 v = *(const f4*)&hb[col][(q8 + 8 * j) * 4];
          s1 += v[0] + v[1] + v[2] + v[3];
          s2 = fmaf(v[0], v[0], s2); s2 = fmaf(v[1], v[1], s2);
          s2 = fmaf(v[2], v[2], s2); s2 = fmaf(v[3], v[3], s2);
        }
        s1 += __shfl_xor(s1, 1, 8); s1 += __shfl_xor(s1, 2, 8);
        s1 += __shfl_xor(s1, 4, 8);
        s2 += __shfl_xor(s2, 1, 8); s2 += __shfl_xor(s2, 2, 8);
        s2 += __shfl_xor(s2, 4, 8);
        const float mu   = s1 * (1.0f / S4_H);
        const float var  = s2 * (1.0f / S4_H) - mu * mu;
        const float rstd = rsqrtf(var + 1e-5f);
#pragma unroll
        for (int j = 0; j < 4; ++j) {
          const int e = (q8 + 8 * j) * 4;
          f4 v = *(const f4*)&hb[col][e];
          const f4 gg = *(const f4*)&ln_g[l * S4_H + e];
          const f4 bb = *(const f4*)&ln_b[l * S4_H + e];
#pragma unroll
          for (int jj = 0; jj < 4; ++jj)
            v[jj] = fmaf((v[jj] - mu) * rstd, gg[jj], bb[jj]);
          *(f4*)&hb[col][e] = v;
        }
      }
    }
    __syncthreads();
  }
  // ---- output (B,H,N,T) + 1x1 conv shortcut (1 row per thread) ----
  // hb reads are row-fixed (contiguous dwords per instruction): conflict-free.
  // 48-B/thread scattered stores are HBM-clean when there are no spills.
  {
    const float sw = sc_W[h], sb = sc_b[h];
    const int bn = seq0 + s;
    const int b = bn >> 10, n = bn & (S4_N - 1);
    float* op = out + (size_t)((b * S4_H + h) * S4_N + n) * S4_T;
#pragma unroll
    for (int qq = 0; qq < 3; ++qq) {
      f4 o;
#pragma unroll
      for (int t4 = 0; t4 < 4; ++t4) {
        const int t = qq * 4 + t4;
        o[t4] = hb[s * S4_T + t][h] + fmaf(sw, xb[s][t], sb);
      }
      *reinterpret_cast<f4*>(op + qq * 4) = o;
    }
  }
}

// ---------------------------------------------------------------------------
// Fallback (no workspace): round-1 fp32 kernel, inline-k variant (exact math).
// ---------------------------------------------------------------------------
#define S4F_SEQ 4
__global__ __launch_bounds__(256) void s4_main_f32(
    const float* __restrict__ x, const float* __restrict__ enc_W,
    const float* __restrict__ enc_b, const float* __restrict__ log_A_real,
    const float* __restrict__ A_imag, const float* __restrict__ C_re,
    const float* __restrict__ C_im, const float* __restrict__ log_dt,
    const float* __restrict__ Dp, const float* __restrict__ out_W,
    const float* __restrict__ out_b, const float* __restrict__ ln_g,
    const float* __restrict__ ln_b, const float* __restrict__ sc_W,
    const float* __restrict__ sc_b, float* __restrict__ out) {
  __shared__ __align__(16) float hbuf[S4F_SEQ][S4_H][S4_T];
  __shared__ __align__(16) float gbuf[S4F_SEQ][S4_H][S4_T];
  __shared__ __align__(16) float kbuf[S4_NL][S4_H][S4_T];
  __shared__ __align__(16) float xbuf[S4F_SEQ][S4_T];
  const int tid = threadIdx.x;
  const int seq0 = blockIdx.x * S4F_SEQ;
  if (tid < S4F_SEQ * S4_T) {
    const int s = tid / S4_T, t = tid - s * S4_T;
    xbuf[s][t] = x[(seq0 + s) * S4_T + t];
  }
  {
    float kk[S4_T];
    s4d_row(log_A_real, A_imag, C_re, C_im, log_dt, tid, kk);
#pragma unroll
    for (int t = 0; t < S4_T; ++t) (&kbuf[0][0][0])[tid * S4_T + t] = kk[t];
  }
  __syncthreads();
  for (int r = tid; r < S4F_SEQ * S4_H; r += 256) {
    const int s = r >> 7, h = r & (S4_H - 1);
    const float ew = enc_W[h], eb = enc_b[h];
#pragma unroll
    for (int t = 0; t < S4_T; ++t) hbuf[s][h][t] = fmaf(xbuf[s][t], ew, eb);
  }
  for (int l = 0; l < S4_NL; ++l) {
    __syncthreads();
    for (int r = tid; r < S4F_SEQ * S4_H; r += 256) {
      const int s = r >> 7, h = r & (S4_H - 1);
      float z[S4_T], kr[S4_T];
#pragma unroll
      for (int t = 0; t < S4_T; ++t) {
        z[t] = hbuf[s][h][t];
        kr[t] = kbuf[l][h][t];
      }
      const float dl = Dp[l * S4_H + h];
#pragma unroll
      for (int t = 0; t < S4_T; ++t) {
        float a = dl * z[t];
#pragma unroll
        for (int ss = 0; ss <= t; ++ss) a = fmaf(kr[t - ss], z[ss], a);
        gbuf[s][h][t] = 0.5f * a * (1.0f + erff(a * 0.70710678118654752f));
      }
    }
    __syncthreads();
    {
      const int op = tid & (S4_H - 1);
      const int sg = tid >> 7;
      const float* __restrict__ W0 = out_W + (size_t)(l * 2 * S4_H + op) * S4_H;
      const float* __restrict__ W1 = W0 + S4_H * S4_H;
      float acc0[2][S4_T], acc1[2][S4_T];
#pragma unroll
      for (int s2 = 0; s2 < 2; ++s2)
#pragma unroll
        for (int t = 0; t < S4_T; ++t) { acc0[s2][t] = 0.f; acc1[s2][t] = 0.f; }
      for (int h0 = 0; h0 < S4_H; h0 += 4) {
        const float4 w0 = *reinterpret_cast<const float4*>(W0 + h0);
        const float4 w1 = *reinterpret_cast<const float4*>(W1 + h0);
        const float w0a[4] = {w0.x, w0.y, w0.z, w0.w};
        const float w1a[4] = {w1.x, w1.y, w1.z, w1.w};
#pragma unroll
        for (int j = 0; j < 4; ++j) {
#pragma unroll
          for (int s2 = 0; s2 < 2; ++s2) {
            const float* gp = &gbuf[2 * sg + s2][h0 + j][0];
            const float4 ga = *reinterpret_cast<const float4*>(gp);
            const float4 gc = *reinterpret_cast<const float4*>(gp + 4);
            const float4 ge = *reinterpret_cast<const float4*>(gp + 8);
            const float gg[S4_T] = {ga.x, ga.y, ga.z, ga.w, gc.x, gc.y,
                                    gc.z, gc.w, ge.x, ge.y, ge.z, ge.w};
#pragma unroll
            for (int t = 0; t < S4_T; ++t) {
              acc0[s2][t] = fmaf(w0a[j], gg[t], acc0[s2][t]);
              acc1[s2][t] = fmaf(w1a[j], gg[t], acc1[s2][t]);
            }
          }
        }
      }
      const float b0 = out_b[l * 2 * S4_H + op];
      const float b1 = out_b[l * 2 * S4_H + S4_H + op];
#pragma unroll
      for (int s2 = 0; s2 < 2; ++s2) {
        const int seq = 2 * sg + s2;
#pragma unroll
        for (int t = 0; t < S4_T; ++t) {
          const float a = acc0[s2][t] + b0;
          const float g = acc1[s2][t] + b1;
          hbuf[seq][op][t] += a * (1.0f / (1.0f + expf(-g)));
        }
      }
    }
    __syncthreads();
    {
      const int col = tid >> 2;
      const int ing = tid & 3;
      if (col < S4F_SEQ * S4_T) {
        const int s = col / S4_T, t = col - s * S4_T;
        float s1 = 0.f, s2v = 0.f;
#pragma unroll
        for (int i = 0; i < S4_H / 4; ++i) {
          const float v = hbuf[s][ing * 32 + i][t];
          s1 += v;
          s2v = fmaf(v, v, s2v);
        }
        s1 += __shfl_xor(s1, 1, 4); s1 += __shfl_xor(s1, 2, 4);
        s2v += __shfl_xor(s2v, 1, 4); s2v += __shfl_xor(s2v, 2, 4);
        const float mu = s1 * (1.0f / S4_H);
        const float var = s2v * (1.0f / S4_H) - mu * mu;
        const float rstd = rsqrtf(var + 1e-5f);
#pragma unroll
        for (int i = 0; i < S4_H / 4; ++i) {
          const int h = ing * 32 + i;
          const float v = hbuf[s][h][t];
          hbuf[s][h][t] =
              fmaf((v - mu) * rstd, ln_g[l * S4_H + h], ln_b[l * S4_H + h]);
        }
      }
    }
  }
  __syncthreads();
  for (int r = tid; r < S4F_SEQ * S4_H; r += 256) {
    const int s = r >> 7, h = r & (S4_H - 1);
    const int bn = seq0 + s;
    const int b = bn >> 10, n = bn & (S4_N - 1);
    const float sw = sc_W[h], sb = sc_b[h];
#pragma unroll
    for (int q = 0; q < 3; ++q) {
      float4 o;
      const float4 hv0 = *reinterpret_cast<const float4*>(&hbuf[s][h][4 * q]);
      const float4 xv = *reinterpret_cast<const float4*>(&xbuf[s][4 * q]);
      o.x = hv0.x + fmaf(sw, xv.x, sb);
      o.y = hv0.y + fmaf(sw, xv.y, sb);
      o.z = hv0.z + fmaf(sw, xv.z, sb);
      o.w = hv0.w + fmaf(sw, xv.w, sb);
      reinterpret_cast<float4*>(out + (size_t)((b * S4_H + h) * S4_N + n) *
                                          S4_T)[q] = o;
    }
  }
}

extern "C" void kernel_launch(void* const* d_in, const int* in_sizes, int n_in,
                              void* d_out, int out_size, void* d_ws,
                              size_t ws_size, hipStream_t stream) {
  const float* x     = (const float*)d_in[0];
  const float* enc_W = (const float*)d_in[1];
  const float* enc_b = (const float*)d_in[2];
  const float* lAr   = (const float*)d_in[3];
  const float* Aim   = (const float*)d_in[4];
  const float* Cre   = (const float*)d_in[5];
  const float* Cim   = (const float*)d_in[6];
  const float* ldt   = (const float*)d_in[7];
  const float* Dp    = (const float*)d_in[8];
  const float* oW    = (const float*)d_in[9];
  const float* ob    = (const float*)d_in[10];
  const float* lg    = (const float*)d_in[11];
  const float* lb    = (const float*)d_in[12];
  const float* scW   = (const float*)d_in[13];
  const float* scb   = (const float*)d_in[14];
  float* out = (float*)d_out;

  const size_t wbytes = (size_t)(S4_NL * 2 * S4_H * S4_H) * sizeof(unsigned short); // 131072
  const size_t kbytes = (size_t)(S4_NL * S4_H * S4_T) * sizeof(float);              // 12288
  if (ws_size >= wbytes + kbytes) {
    unsigned short* Wbf = (unsigned short*)d_ws;
    float* kws = (float*)((char*)d_ws + wbytes);
    s4_prep<<<64, 256, 0, stream>>>(oW, lAr, Aim, Cre, Cim, ldt, Wbf, kws);
    s4_512<<<S4_GRID, 512, 0, stream>>>(x, enc_W, enc_b, Dp, ob, lg,
                                        lb, scW, scb, Wbf, kws, out);
  } else {
    s4_main_f32<<<S4_BN / S4F_SEQ, 256, 0, stream>>>(
        x, enc_W, enc_b, lAr, Aim, Cre, Cim, ldt, Dp, oW, ob, lg, lb, scW,
        scb, out);
  }
}

// Round 16
// 135.336 us; speedup vs baseline: 1.1353x; 1.0214x over previous
//
#include <hip/hip_runtime.h>
#include <math.h>

#define S4_H   128
#define S4_HP  136          // padded leading dim (dword stride 136 ≡ 8 mod 32)
#define S4_T   12
#define S4_TT  48           // 4 seqs * 12 timesteps
#define S4_S2  32
#define S4_SEQ 4
#define S4_NL  2
#define S4_N   1024
#define S4_BN  (16 * 1024)

typedef float f4 __attribute__((ext_vector_type(4)));
typedef short s8v __attribute__((ext_vector_type(8)));   // 8 bf16 bit-patterns

__device__ __forceinline__ unsigned short f2bf(float f) {
  unsigned int u = __builtin_bit_cast(unsigned int, f);
  u += 0x7fffu + ((u >> 16) & 1u);   // RNE
  return (unsigned short)(u >> 16);
}

// gelu(x) ~= x * sigmoid(1.5957691x(1 + 0.044715x^2))  (tanh form)
__device__ __forceinline__ float fast_gelu(float x) {
  const float u = 1.5957691216057308f * x * fmaf(0.044715f, x * x, 1.0f);
  return x * __builtin_amdgcn_rcpf(1.0f + __expf(-u));
}
__device__ __forceinline__ float fast_sigmoid(float g) {
  return __builtin_amdgcn_rcpf(1.0f + __expf(-g));
}

// ---------------------------------------------------------------------------
// S4D kernel row: k[h][t] = 2*Re( sum_n C_n * exp(dtA_n)^t ), ZOH discretized.
// ---------------------------------------------------------------------------
__device__ __forceinline__ void s4d_row(const float* __restrict__ log_A_real,
                                        const float* __restrict__ A_imag,
                                        const float* __restrict__ C_re,
                                        const float* __restrict__ C_im,
                                        const float* __restrict__ log_dt,
                                        int lh, float* kk) {
  const float dt = expf(log_dt[lh]);
#pragma unroll
  for (int t = 0; t < S4_T; ++t) kk[t] = 0.f;
  const int base = lh * S4_S2;
  for (int n = 0; n < S4_S2; ++n) {
    const float ar = -expf(log_A_real[base + n]);
    const float ai = A_imag[base + n];
    const float m  = expf(ar * dt);
    const float di = ai * dt;
    float sdi, cdi;
    sincosf(di, &sdi, &cdi);
    const float er = m * cdi, ei = m * sdi;           // exp(dt*A)
    const float inv = 1.0f / (ar * ar + ai * ai);
    const float x0 = er - 1.0f;
    const float qr = (x0 * ar + ei * ai) * inv;       // (exp(dtA)-1)/A
    const float qi = (ei * ar - x0 * ai) * inv;
    const float c0r = C_re[base + n], c0i = C_im[base + n];
    const float cr = c0r * qr - c0i * qi;             // C_tilde
    const float ci = c0r * qi + c0i * qr;
    float vr = 1.f, vi = 0.f;                         // V = exp(dtA)^t
#pragma unroll
    for (int t = 0; t < S4_T; ++t) {
      kk[t] = fmaf(cr, vr, fmaf(-ci, vi, kk[t]));
      const float nvr = vr * er - vi * ei;
      vi = vr * ei + vi * er;
      vr = nvr;
    }
  }
#pragma unroll
  for (int t = 0; t < S4_T; ++t) kk[t] *= 2.0f;
}

// prep: W fp32 -> bf16 bits in ws, and S4D kernel k into ws.
__global__ __launch_bounds__(256) void s4_prep(
    const float* __restrict__ oW, const float* __restrict__ lAr,
    const float* __restrict__ Aim, const float* __restrict__ Cre,
    const float* __restrict__ Cim, const float* __restrict__ ldt,
    unsigned short* __restrict__ Wbf, float* __restrict__ kout) {
  const int tid = blockIdx.x * 256 + (int)threadIdx.x;
  const int i = tid * 4;
  if (i < S4_NL * 2 * S4_H * S4_H) {
    const f4 v = *reinterpret_cast<const f4*>(&oW[i]);
    ushort4 o;
    o.x = f2bf(v[0]); o.y = f2bf(v[1]); o.z = f2bf(v[2]); o.w = f2bf(v[3]);
    *reinterpret_cast<ushort4*>(&Wbf[i]) = o;
  }
  if (tid < S4_NL * S4_H) {
    float kk[S4_T];
    s4d_row(lAr, Aim, Cre, Cim, ldt, tid, kk);
#pragma unroll
    for (int t = 0; t < S4_T; ++t) kout[tid * S4_T + t] = kk[t];
  }
}

// ---------------------------------------------------------------------------
// Fused S4 block, 512 threads (8 waves), R3 memory patterns for hb/gb.
// Output phase: chunk-remapped so each wave store instruction covers
// consecutive 16-B chunks of contiguous 192-B h-runs (sector-aligned,
// no partial-line RMW regardless of wave drift).
// ---------------------------------------------------------------------------
__global__ __launch_bounds__(512, 8) void s4_512(
    const float* __restrict__ x, const float* __restrict__ enc_W,
    const float* __restrict__ enc_b, const float* __restrict__ Dp,
    const float* __restrict__ out_b, const float* __restrict__ ln_g,
    const float* __restrict__ ln_b, const float* __restrict__ sc_W,
    const float* __restrict__ sc_b, const unsigned short* __restrict__ Wbf,
    const float* __restrict__ kws, float* __restrict__ out) {
  __shared__ __align__(16) float hb[S4_TT][S4_HP];           // 26112 B (fp32)
  __shared__ __align__(16) unsigned short gb[S4_TT][S4_HP];  // 13056 B (bf16)
  __shared__ __align__(16) float xb[S4_SEQ][S4_T];           // 192 B

  const int tid  = threadIdx.x;
  const int w    = tid >> 6;          // wave 0..7
  const int lane = tid & 63;
  const int s    = tid >> 7;          // owned sequence (conv), 0..3
  const int h    = tid & (S4_H - 1);  // owned channel (conv)
  const int seq0 = blockIdx.x * S4_SEQ;

  if (tid < S4_SEQ * S4_T) {
    const int ss = tid / S4_T, t = tid - ss * S4_T;
    xb[ss][t] = x[(seq0 + ss) * S4_T + t];
  }
  __syncthreads();

  for (int l = 0; l < S4_NL; ++l) {
    // ---- conv phase (1 row per thread); l==0 fuses encoder & seeds hb ----
    {
      const float* kp = &kws[(l * S4_H + h) * S4_T];
      const f4 k0 = *(const f4*)(kp), k1 = *(const f4*)(kp + 4),
               k2 = *(const f4*)(kp + 8);
      const float kr[S4_T] = {k0[0], k0[1], k0[2], k0[3], k1[0], k1[1],
                              k1[2], k1[3], k2[0], k2[1], k2[2], k2[3]};
      const float dl = Dp[l * S4_H + h];
      float z[S4_T];
      if (l == 0) {
        const float ew = enc_W[h], eb = enc_b[h];
#pragma unroll
        for (int t = 0; t < S4_T; ++t) {
          z[t] = fmaf(xb[s][t], ew, eb);
          hb[s * S4_T + t][h] = z[t];
        }
      } else {
#pragma unroll
        for (int t = 0; t < S4_T; ++t) z[t] = hb[s * S4_T + t][h];
      }
#pragma unroll
      for (int t = 0; t < S4_T; ++t) {
        float a = dl * z[t];
#pragma unroll
        for (int ss = 0; ss <= t; ++ss) a = fmaf(kr[t - ss], z[ss], a);
        gb[s * S4_T + t][h] = f2bf(fast_gelu(a));
      }
    }
    __syncthreads();
    // ---- channel mix: wave w owns val tile w, gate tile 8+w ----
    {
      const int r = lane & 15;        // N index (tt within tile) / A row offset
      const int q = lane >> 4;        // k-group / D row group
      f4 accV[3] = {}, accG[3] = {};
      const unsigned short* WL = Wbf + (size_t)l * 2 * S4_H * S4_H;
      const unsigned short* wVp = WL + (size_t)(w * 16 + r) * S4_H + q * 8;
      const unsigned short* wGp = WL + (size_t)((8 + w) * 16 + r) * S4_H + q * 8;
#pragma unroll
      for (int ks = 0; ks < 4; ++ks) {
        const s8v afV = *(const s8v*)(wVp + ks * 32);
        const s8v afG = *(const s8v*)(wGp + ks * 32);
#pragma unroll
        for (int n = 0; n < 3; ++n) {
          const s8v bfv =
              *(const s8v*)(&gb[n * 16 + r][ks * 32 + q * 8]);
          accV[n] = __builtin_amdgcn_mfma_f32_16x16x32_bf16(afV, bfv, accV[n],
                                                            0, 0, 0);
          accG[n] = __builtin_amdgcn_mfma_f32_16x16x32_bf16(afG, bfv, accG[n],
                                                            0, 0, 0);
        }
      }
      // GLU + bias + residual RMW into hb (unique 16B quads per lane)
      const int oV = w * 16 + 4 * q;
      const f4 bV = *(const f4*)&out_b[l * 2 * S4_H + oV];
      const f4 bG = *(const f4*)&out_b[l * 2 * S4_H + S4_H + oV];
#pragma unroll
      for (int n = 0; n < 3; ++n) {
        f4* hp = reinterpret_cast<f4*>(&hb[n * 16 + r][oV]);
        f4 hv = *hp;
#pragma unroll
        for (int j = 0; j < 4; ++j) {
          const float a = accV[n][j] + bV[j];
          const float g = accG[n][j] + bG[j];
          hv[j] += a * fast_sigmoid(g);
        }
        *hp = hv;
      }
    }
    __syncthreads();
    // ---- LayerNorm in-place: 8 lanes per tt column ----
    {
      const int col = tid >> 3;       // 0..63 (cols >=48 idle)
      const int q8  = tid & 7;
      if (col < S4_TT) {
        float s1 = 0.f, s2 = 0.f;
#pragma unroll
        for (int j = 0; j < 4; ++j) {
          const f4 v = *(const f4*)&hb[col][(q8 + 8 * j) * 4];
          s1 += v[0] + v[1] + v[2] + v[3];
          s2 = fmaf(v[0], v[0], s2); s2 = fmaf(v[1], v[1], s2);
          s2 = fmaf(v[2], v[2], s2); s2 = fmaf(v[3], v[3], s2);
        }
        s1 += __shfl_xor(s1, 1, 8); s1 += __shfl_xor(s1, 2, 8);
        s1 += __shfl_xor(s1, 4, 8);
        s2 += __shfl_xor(s2, 1, 8); s2 += __shfl_xor(s2, 2, 8);
        s2 += __shfl_xor(s2, 4, 8);
        const float mu   = s1 * (1.0f / S4_H);
        const float var  = s2 * (1.0f / S4_H) - mu * mu;
        const float rstd = rsqrtf(var + 1e-5f);
#pragma unroll
        for (int j = 0; j < 4; ++j) {
          const int e = (q8 + 8 * j) * 4;
          f4 v = *(const f4*)&hb[col][e];
          const f4 gg = *(const f4*)&ln_g[l * S4_H + e];
          const f4 bb = *(const f4*)&ln_b[l * S4_H + e];
#pragma unroll
          for (int jj = 0; jj < 4; ++jj)
            v[jj] = fmaf((v[jj] - mu) * rstd, gg[jj], bb[jj]);
          *(f4*)&hb[col][e] = v;
        }
      }
    }
    __syncthreads();
  }
  // ---- output: chunk-remapped, sector-aligned coalesced writes ----
  // Block output = 128 h-runs x 192 B contiguous (seqs n0..n0+3 per h).
  // Chunk c = h*12 + j covers floats e = 4j..4j+3 of run h (e = s*12+t = tt).
  {
    const int b  = seq0 >> 10;             // batch (block never spans b)
    const int n0 = seq0 & (S4_N - 1);
    const float* xbf = &xb[0][0];
#pragma unroll
    for (int k = 0; k < 3; ++k) {
      const int c  = tid + 512 * k;        // 0..1535
      const int hh = c / 12;               // magic-mul division
      const int j  = c - 12 * hh;
      const float sw = sc_W[hh], sb = sc_b[hh];
      const f4 xc = *(const f4*)&xbf[4 * j];   // x[e] for e = 4j..4j+3
      f4 o;
#pragma unroll
      for (int i = 0; i < 4; ++i)
        o[i] = hb[4 * j + i][hh] + fmaf(sw, xc[i], sb);
      float* op = out + (size_t)((b * S4_H + hh) * S4_N + n0) * S4_T + 4 * j;
      *reinterpret_cast<f4*>(op) = o;
    }
  }
}

// ---------------------------------------------------------------------------
// Fallback (no workspace): round-1 fp32 kernel, inline-k variant (exact math).
// ---------------------------------------------------------------------------
#define S4F_SEQ 4
__global__ __launch_bounds__(256) void s4_main_f32(
    const float* __restrict__ x, const float* __restrict__ enc_W,
    const float* __restrict__ enc_b, const float* __restrict__ log_A_real,
    const float* __restrict__ A_imag, const float* __restrict__ C_re,
    const float* __restrict__ C_im, const float* __restrict__ log_dt,
    const float* __restrict__ Dp, const float* __restrict__ out_W,
    const float* __restrict__ out_b, const float* __restrict__ ln_g,
    const float* __restrict__ ln_b, const float* __restrict__ sc_W,
    const float* __restrict__ sc_b, float* __restrict__ out) {
  __shared__ __align__(16) float hbuf[S4F_SEQ][S4_H][S4_T];
  __shared__ __align__(16) float gbuf[S4F_SEQ][S4_H][S4_T];
  __shared__ __align__(16) float kbuf[S4_NL][S4_H][S4_T];
  __shared__ __align__(16) float xbuf[S4F_SEQ][S4_T];
  const int tid = threadIdx.x;
  const int seq0 = blockIdx.x * S4F_SEQ;
  if (tid < S4F_SEQ * S4_T) {
    const int s = tid / S4_T, t = tid - s * S4_T;
    xbuf[s][t] = x[(seq0 + s) * S4_T + t];
  }
  {
    float kk[S4_T];
    s4d_row(log_A_real, A_imag, C_re, C_im, log_dt, tid, kk);
#pragma unroll
    for (int t = 0; t < S4_T; ++t) (&kbuf[0][0][0])[tid * S4_T + t] = kk[t];
  }
  __syncthreads();
  for (int r = tid; r < S4F_SEQ * S4_H; r += 256) {
    const int s = r >> 7, h = r & (S4_H - 1);
    const float ew = enc_W[h], eb = enc_b[h];
#pragma unroll
    for (int t = 0; t < S4_T; ++t) hbuf[s][h][t] = fmaf(xbuf[s][t], ew, eb);
  }
  for (int l = 0; l < S4_NL; ++l) {
    __syncthreads();
    for (int r = tid; r < S4F_SEQ * S4_H; r += 256) {
      const int s = r >> 7, h = r & (S4_H - 1);
      float z[S4_T], kr[S4_T];
#pragma unroll
      for (int t = 0; t < S4_T; ++t) {
        z[t] = hbuf[s][h][t];
        kr[t] = kbuf[l][h][t];
      }
      const float dl = Dp[l * S4_H + h];
#pragma unroll
      for (int t = 0; t < S4_T; ++t) {
        float a = dl * z[t];
#pragma unroll
        for (int ss = 0; ss <= t; ++ss) a = fmaf(kr[t - ss], z[ss], a);
        gbuf[s][h][t] = 0.5f * a * (1.0f + erff(a * 0.70710678118654752f));
      }
    }
    __syncthreads();
    {
      const int op = tid & (S4_H - 1);
      const int sg = tid >> 7;
      const float* __restrict__ W0 = out_W + (size_t)(l * 2 * S4_H + op) * S4_H;
      const float* __restrict__ W1 = W0 + S4_H * S4_H;
      float acc0[2][S4_T], acc1[2][S4_T];
#pragma unroll
      for (int s2 = 0; s2 < 2; ++s2)
#pragma unroll
        for (int t = 0; t < S4_T; ++t) { acc0[s2][t] = 0.f; acc1[s2][t] = 0.f; }
      for (int h0 = 0; h0 < S4_H; h0 += 4) {
        const float4 w0 = *reinterpret_cast<const float4*>(W0 + h0);
        const float4 w1 = *reinterpret_cast<const float4*>(W1 + h0);
        const float w0a[4] = {w0.x, w0.y, w0.z, w0.w};
        const float w1a[4] = {w1.x, w1.y, w1.z, w1.w};
#pragma unroll
        for (int j = 0; j < 4; ++j) {
#pragma unroll
          for (int s2 = 0; s2 < 2; ++s2) {
            const float* gp = &gbuf[2 * sg + s2][h0 + j][0];
            const float4 ga = *reinterpret_cast<const float4*>(gp);
            const float4 gc = *reinterpret_cast<const float4*>(gp + 4);
            const float4 ge = *reinterpret_cast<const float4*>(gp + 8);
            const float gg[S4_T] = {ga.x, ga.y, ga.z, ga.w, gc.x, gc.y,
                                    gc.z, gc.w, ge.x, ge.y, ge.z, ge.w};
#pragma unroll
            for (int t = 0; t < S4_T; ++t) {
              acc0[s2][t] = fmaf(w0a[j], gg[t], acc0[s2][t]);
              acc1[s2][t] = fmaf(w1a[j], gg[t], acc1[s2][t]);
            }
          }
        }
      }
      const float b0 = out_b[l * 2 * S4_H + op];
      const float b1 = out_b[l * 2 * S4_H + S4_H + op];
#pragma unroll
      for (int s2 = 0; s2 < 2; ++s2) {
        const int seq = 2 * sg + s2;
#pragma unroll
        for (int t = 0; t < S4_T; ++t) {
          const float a = acc0[s2][t] + b0;
          const float g = acc1[s2][t] + b1;
          hbuf[seq][op][t] += a * (1.0f / (1.0f + expf(-g)));
        }
      }
    }
    __syncthreads();
    {
      const int col = tid >> 2;
      const int ing = tid & 3;
      if (col < S4F_SEQ * S4_T) {
        const int s = col / S4_T, t = col - s * S4_T;
        float s1 = 0.f, s2v = 0.f;
#pragma unroll
        for (int i = 0; i < S4_H / 4; ++i) {
          const float v = hbuf[s][ing * 32 + i][t];
          s1 += v;
          s2v = fmaf(v, v, s2v);
        }
        s1 += __shfl_xor(s1, 1, 4); s1 += __shfl_xor(s1, 2, 4);
        s2v += __shfl_xor(s2v, 1, 4); s2v += __shfl_xor(s2v, 2, 4);
        const float mu = s1 * (1.0f / S4_H);
        const float var = s2v * (1.0f / S4_H) - mu * mu;
        const float rstd = rsqrtf(var + 1e-5f);
#pragma unroll
        for (int i = 0; i < S4_H / 4; ++i) {
          const int h = ing * 32 + i;
          const float v = hbuf[s][h][t];
          hbuf[s][h][t] =
              fmaf((v - mu) * rstd, ln_g[l * S4_H + h], ln_b[l * S4_H + h]);
        }
      }
    }
  }
  __syncthreads();
  for (int r = tid; r < S4F_SEQ * S4_H; r += 256) {
    const int s = r >> 7, h = r & (S4_H - 1);
    const int bn = seq0 + s;
    const int b = bn >> 10, n = bn & (S4_N - 1);
    const float sw = sc_W[h], sb = sc_b[h];
#pragma unroll
    for (int q = 0; q < 3; ++q) {
      float4 o;
      const float4 hv0 = *reinterpret_cast<const float4*>(&hbuf[s][h][4 * q]);
      const float4 xv = *reinterpret_cast<const float4*>(&xbuf[s][4 * q]);
      o.x = hv0.x + fmaf(sw, xv.x, sb);
      o.y = hv0.y + fmaf(sw, xv.y, sb);
      o.z = hv0.z + fmaf(sw, xv.z, sb);
      o.w = hv0.w + fmaf(sw, xv.w, sb);
      reinterpret_cast<float4*>(out + (size_t)((b * S4_H + h) * S4_N + n) *
                                          S4_T)[q] = o;
    }
  }
}

extern "C" void kernel_launch(void* const* d_in, const int* in_sizes, int n_in,
                              void* d_out, int out_size, void* d_ws,
                              size_t ws_size, hipStream_t stream) {
  const float* x     = (const float*)d_in[0];
  const float* enc_W = (const float*)d_in[1];
  const float* enc_b = (const float*)d_in[2];
  const float* lAr   = (const float*)d_in[3];
  const float* Aim   = (const float*)d_in[4];
  const float* Cre   = (const float*)d_in[5];
  const float* Cim   = (const float*)d_in[6];
  const float* ldt   = (const float*)d_in[7];
  const float* Dp    = (const float*)d_in[8];
  const float* oW    = (const float*)d_in[9];
  const float* ob    = (const float*)d_in[10];
  const float* lg    = (const float*)d_in[11];
  const float* lb    = (const float*)d_in[12];
  const float* scW   = (const float*)d_in[13];
  const float* scb   = (const float*)d_in[14];
  float* out = (float*)d_out;

  const size_t wbytes = (size_t)(S4_NL * 2 * S4_H * S4_H) * sizeof(unsigned short); // 131072
  const size_t kbytes = (size_t)(S4_NL * S4_H * S4_T) * sizeof(float);              // 12288
  if (ws_size >= wbytes + kbytes) {
    unsigned short* Wbf = (unsigned short*)d_ws;
    float* kws = (float*)((char*)d_ws + wbytes);
    s4_prep<<<64, 256, 0, stream>>>(oW, lAr, Aim, Cre, Cim, ldt, Wbf, kws);
    s4_512<<<S4_BN / S4_SEQ, 512, 0, stream>>>(x, enc_W, enc_b, Dp, ob, lg,
                                               lb, scW, scb, Wbf, kws, out);
  } else {
    s4_main_f32<<<S4_BN / S4F_SEQ, 256, 0, stream>>>(
        x, enc_W, enc_b, lAr, Aim, Cre, Cim, ldt, Dp, oW, ob, lg, lb, scW,
        scb, out);
  }
}